// Round 19
// baseline (112.590 us; speedup 1.0000x reference)
//
#include <hip/hip_runtime.h>

typedef short short8 __attribute__((ext_vector_type(8)));
typedef float f32x16 __attribute__((ext_vector_type(16)));
typedef int   int4v  __attribute__((ext_vector_type(4)));
typedef int   int2v  __attribute__((ext_vector_type(2)));

#define T_TOK 4096
#define NH    32
#define NKV   8
#define HD    128
#define QREP  (NH / NKV)

__device__ __forceinline__ unsigned short f32_to_bf16_bits(float x) {
  union { float f; unsigned u; } a; a.f = x;
  unsigned r = a.u + 0x7fffu + ((a.u >> 16) & 1u);  // round-to-nearest-even
  return (unsigned short)(r >> 16);
}
__device__ __forceinline__ unsigned pack_bf16(float a, float b) {
  return (unsigned)f32_to_bf16_bits(a) | ((unsigned)f32_to_bf16_bits(b) << 16);
}
// hardware packed f32->bf16 (RNE), lo=a hi=b
__device__ __forceinline__ unsigned cvtpk(float a, float b) {
  unsigned r;
  asm("v_cvt_pk_bf16_f32 %0, %1, %2" : "=v"(r) : "v"(a), "v"(b));
  return r;
}

// async global->LDS, 16B per lane; lds dest = wave-uniform base + lane*16
__device__ __forceinline__ void stage16(const unsigned short* g, unsigned short* l) {
  __builtin_amdgcn_global_load_lds(
      (const __attribute__((address_space(1))) unsigned int*)g,
      (__attribute__((address_space(3))) unsigned int*)l,
      16, 0, 0);
}

// P (f32x16, one 32-key tile) -> bf16 A-fragment for sub-tile st (k = 8*hi + j)
// Verified shfl_xor(32) + select form (round-13 base).
__device__ __forceinline__ short8 p_frag(const f32x16& p, int st, int hi) {
  unsigned c01 = cvtpk(p[8*st+0], p[8*st+1]);
  unsigned c23 = cvtpk(p[8*st+2], p[8*st+3]);
  unsigned c45 = cvtpk(p[8*st+4], p[8*st+5]);
  unsigned c67 = cvtpk(p[8*st+6], p[8*st+7]);
  unsigned x01 = (unsigned)__shfl_xor((int)c01, 32, 64);
  unsigned x23 = (unsigned)__shfl_xor((int)c23, 32, 64);
  unsigned x45 = (unsigned)__shfl_xor((int)c45, 32, 64);
  unsigned x67 = (unsigned)__shfl_xor((int)c67, 32, 64);
  int4v pi;
  pi[0] = (int)(hi ? x45 : c01);
  pi[1] = (int)(hi ? x67 : c23);
  pi[2] = (int)(hi ? c45 : x01);
  pi[3] = (int)(hi ? c67 : x23);
  return __builtin_bit_cast(short8, pi);
}

// ---- prep A: K f32 [T][NKV][HD] -> fragment-packed bf16
__global__ __launch_bounds__(256)
void pack_k(const float* __restrict__ k, unsigned short* __restrict__ kf,
            const int* __restrict__ nseq) {
  int tid  = blockIdx.x * 256 + threadIdx.x;   // 2^19 threads
  int lane = tid & 63;
  int dc   = (tid >> 6) & 7;
  int gt   = (tid >> 9) & (T_TOK / 32 - 1);
  int kvh  = tid >> 16;
  int c = lane & 31, hi = lane >> 5;
  int token = gt * 32 + c;
  const float* src = k + ((size_t)token * NKV + kvh) * HD + dc * 16 + hi * 8;
  float4 a  = *reinterpret_cast<const float4*>(src);
  float4 b4 = *reinterpret_cast<const float4*>(src + 4);
  const int B = *nseq, S = T_TOK / B, S32 = S >> 5;
  int bseq = gt / S32, tile = gt - bseq * S32;
  size_t off = ((size_t)(bseq * NKV + kvh) * S32 + tile) * 4096 + dc * 512 + lane * 8;
  int4v wv; wv[0] = (int)pack_bf16(a.x, a.y);   wv[1] = (int)pack_bf16(a.z, a.w);
            wv[2] = (int)pack_bf16(b4.x, b4.y); wv[3] = (int)pack_bf16(b4.z, b4.w);
  *reinterpret_cast<int4v*>(kf + off) = wv;
}

// ---- prep B: V f32 [T][NKV][HD] -> fragment-packed bf16 (PV B-operand order)
__global__ __launch_bounds__(256)
void pack_v(const float* __restrict__ v, unsigned short* __restrict__ vf,
            const int* __restrict__ nseq) {
  int tid  = blockIdx.x * 256 + threadIdx.x;
  int lane = tid & 63;
  int idx  = (tid >> 6) & 7;                   // st*4 + dt
  int gt   = (tid >> 9) & (T_TOK / 32 - 1);
  int kvh  = tid >> 16;
  int c = lane & 31, hi = lane >> 5;
  int st = idx >> 2, dt = idx & 3;
  int token0 = gt * 32 + 16 * st + 8 * hi;
  const float* src = v + ((size_t)token0 * NKV + kvh) * HD + dt * 32 + c;
  unsigned u[4];
  #pragma unroll
  for (int jj = 0; jj < 4; ++jj) {
    float a = src[(size_t)(2 * jj)     * (NKV * HD)];
    float b = src[(size_t)(2 * jj + 1) * (NKV * HD)];
    u[jj] = pack_bf16(a, b);
  }
  const int B = *nseq, S = T_TOK / B, S32 = S >> 5;
  int bseq = gt / S32, tile = gt - bseq * S32;
  size_t off = ((size_t)(bseq * NKV + kvh) * S32 + tile) * 4096 + idx * 512 + lane * 8;
  int4v wv; wv[0] = (int)u[0]; wv[1] = (int)u[1]; wv[2] = (int)u[2]; wv[3] = (int)u[3];
  *reinterpret_cast<int4v*>(vf + off) = wv;
}

// ---- main kernel: K LDS dbuf (32KB), V direct, XCD-pinned kvh (T1) ----
// launch_bounds(256,4): VGPR 84 fits the 128 cap; raises residency ceiling to 4 blocks/CU.
__global__ __launch_bounds__(256, 4)
void attn_fwd_fast(const float* __restrict__ q,
                   const unsigned short* __restrict__ kfp,
                   const unsigned short* __restrict__ vfp,
                   const int* __restrict__ nseq,
                   float* __restrict__ out)
{
  __shared__ __align__(16) unsigned short sm[16384];   // 32 KB

  const int bid  = blockIdx.x;
  // XCD-pinning remap (bijective, 1024 % 8 == 0): XCD (= bid&7) <- kvh.
  // All 128 blocks of one kvh share one XCD-L2 -> aligned V scans hit L2.
  const int vid  = (bid & 7) * 128 + (bid >> 3);
  const int kvh  = vid >> 7;
  const int rem  = vid & 127;
  const int z    = rem >> 2;              // row-slot 0..31, ascending with bid
  const int h    = kvh * QREP + (rem & 3);
  const int w    = threadIdx.x >> 6;
  const int lane = threadIdx.x & 63;
  const int c    = lane & 31;
  const int hi   = lane >> 5;

  const int B = *nseq;
  const int S = T_TOK / B;
  const int S32 = S >> 5;
  const int RBS = S >> 7;                 // 128-row blocks per sequence

  // longest-first: rloc descending with dispatch order, then sequence
  const int rloc = RBS - 1 - (z / B);
  const int seq  = z - (z / B) * B;
  const int rb   = seq * RBS + rloc;

  const int rbase = rb * 128;
  const int row0  = rbase + w * 32;
  const int s0    = row0 - seq * S;
  const int ntw   = s0 / 32 + 1;
  const int diag  = ntw - 1;
  const int npb   = (rloc * 4 + 4) >> 1;  // K-pair count

  const float sl2e = 0.08838834764831845f * 1.4426950408889634f;

  const unsigned short* kf_blk = kfp + ((size_t)(seq * NKV + kvh) * S32) * 4096;
  const unsigned short* vfb = vfp + ((size_t)(seq * NKV + kvh) * S32) * 4096 + lane * 8;

  // ---- Q startup: f32 coalesced -> bf16 swizzled tile using the whole 32KB ----
  char* qlds = (char*)sm;
  {
    #pragma unroll
    for (int j = 0; j < 16; ++j) {
      const int rowb = w * 32 + 2 * j + hi;
      const float* gsrc = q + ((size_t)(rbase + rowb) * NH + h) * HD + 4 * c;
      float4 a = *reinterpret_cast<const float4*>(gsrc);
      int2v u;
      u[0] = (int)cvtpk(a.x * sl2e, a.y * sl2e);
      u[1] = (int)cvtpk(a.z * sl2e, a.w * sl2e);
      const int off = (rowb * 256 + 8 * c) ^ ((rowb & 7) << 4);
      *reinterpret_cast<int2v*>(qlds + off) = u;
    }
  }
  __syncthreads();

  short8 qf[8];
  {
    const int rowb = w * 32 + c;
    #pragma unroll
    for (int dc = 0; dc < 8; ++dc) {
      const int off = (rowb * 256 + dc * 32 + hi * 16) ^ ((c & 7) << 4);
      qf[dc] = *reinterpret_cast<const short8*>(qlds + off);
    }
  }
  __syncthreads();   // all Q reads done before K staging overwrites

  // ---- prologue: stage K pair 0 into buf0 (sm[0..8192)) ----
  {
    const unsigned short* src = kf_blk + (size_t)(w >> 1) * 4096 + (w & 1) * 2048 + lane * 8;
    unsigned short* dst = sm + w * 2048;
    #pragma unroll
    for (int j = 0; j < 4; ++j) stage16(src + j * 512, dst + j * 512);
  }
  __syncthreads();

  f32x16 o0 = {}, o1 = {}, o2 = {}, o3 = {};
  float m = -1e30f, l = 0.0f;

  for (int i = 0; i < npb; ++i) {
    const unsigned short* curK = sm + (i & 1) * 8192;

    if (i + 1 < npb) {   // stage next K pair into other buffer
      const unsigned short* src =
          kf_blk + (size_t)(2 * (i + 1) + (w >> 1)) * 4096 + (w & 1) * 2048 + lane * 8;
      unsigned short* dst = sm + ((i + 1) & 1) * 8192 + w * 2048;
      #pragma unroll
      for (int j = 0; j < 4; ++j) stage16(src + j * 512, dst + j * 512);
    }

    if (2 * i < ntw) {   // wave-uniform: this wave still has work
      const int ta = 2 * i, tb = 2 * i + 1;
      const unsigned short* kA = curK + lane * 8;
      const unsigned short* kB = curK + 4096 + lane * 8;

      f32x16 sa = {}, sb = {};
      __builtin_amdgcn_s_setprio(1);
      #pragma unroll
      for (int dc = 0; dc < 8; ++dc) {
        short8 ka  = *reinterpret_cast<const short8*>(kA + dc * 512);
        short8 kb8 = *reinterpret_cast<const short8*>(kB + dc * 512);
        sa = __builtin_amdgcn_mfma_f32_32x32x16_bf16(ka,  qf[dc], sa, 0, 0, 0);
        sb = __builtin_amdgcn_mfma_f32_32x32x16_bf16(kb8, qf[dc], sb, 0, 0, 0);
      }
      __builtin_amdgcn_s_setprio(0);

      const int qs = s0 + c;
      if (tb >= diag) {
        #pragma unroll
        for (int r = 0; r < 16; ++r) {
          int key = tb * 32 + (r & 3) + 8 * (r >> 2) + 4 * hi;
          if (key > qs) sb[r] = -1e30f;
        }
      }
      if (ta >= diag) {
        #pragma unroll
        for (int r = 0; r < 16; ++r) {
          int key = ta * 32 + (r & 3) + 8 * (r >> 2) + 4 * hi;
          if (key > qs) sa[r] = -1e30f;
        }
      }

      float pm = fmaxf(sa[0], sb[0]);
      #pragma unroll
      for (int r = 1; r < 16; ++r) pm = fmaxf(pm, fmaxf(sa[r], sb[r]));
      pm = fmaxf(pm, __shfl_xor(pm, 32));

      if (!__all(pm - m <= 8.0f)) {   // T13 defer-max (log2 domain)
        float mn = fmaxf(m, pm);
        float al = __builtin_amdgcn_exp2f(m - mn);
        m = mn;
        l *= al;
        #pragma unroll
        for (int r = 0; r < 16; ++r) {
          float ar = __shfl(al, (r & 3) + 8 * (r >> 2) + 4 * hi, 64);
          o0[r] *= ar; o1[r] *= ar; o2[r] *= ar; o3[r] *= ar;
        }
      }

      float rs = 0.0f;
      f32x16 pA, pB;
      #pragma unroll
      for (int r = 0; r < 16; ++r) {
        pA[r] = __builtin_amdgcn_exp2f(sa[r] - m);
        pB[r] = __builtin_amdgcn_exp2f(sb[r] - m);
        rs += pA[r] + pB[r];
      }
      rs += __shfl_xor(rs, 32);
      l += rs;

      short8 fa0 = p_frag(pA, 0, hi), fa1 = p_frag(pA, 1, hi);
      short8 fb0 = p_frag(pB, 0, hi), fb1 = p_frag(pB, 1, hi);

      // V fragments direct from packed global (coalesced 1KB/instr, L2-pinned)
      const unsigned short* va = vfb + (size_t)ta * 4096;
      const unsigned short* vb = vfb + (size_t)tb * 4096;
      short8 va00 = *reinterpret_cast<const short8*>(va);
      short8 va01 = *reinterpret_cast<const short8*>(va + 512);
      short8 va02 = *reinterpret_cast<const short8*>(va + 1024);
      short8 va03 = *reinterpret_cast<const short8*>(va + 1536);
      short8 va10 = *reinterpret_cast<const short8*>(va + 2048);
      short8 va11 = *reinterpret_cast<const short8*>(va + 2560);
      short8 va12 = *reinterpret_cast<const short8*>(va + 3072);
      short8 va13 = *reinterpret_cast<const short8*>(va + 3584);
      __builtin_amdgcn_s_setprio(1);
      o0 = __builtin_amdgcn_mfma_f32_32x32x16_bf16(fa0, va00, o0, 0, 0, 0);
      o1 = __builtin_amdgcn_mfma_f32_32x32x16_bf16(fa0, va01, o1, 0, 0, 0);
      o2 = __builtin_amdgcn_mfma_f32_32x32x16_bf16(fa0, va02, o2, 0, 0, 0);
      o3 = __builtin_amdgcn_mfma_f32_32x32x16_bf16(fa0, va03, o3, 0, 0, 0);
      o0 = __builtin_amdgcn_mfma_f32_32x32x16_bf16(fa1, va10, o0, 0, 0, 0);
      o1 = __builtin_amdgcn_mfma_f32_32x32x16_bf16(fa1, va11, o1, 0, 0, 0);
      o2 = __builtin_amdgcn_mfma_f32_32x32x16_bf16(fa1, va12, o2, 0, 0, 0);
      o3 = __builtin_amdgcn_mfma_f32_32x32x16_bf16(fa1, va13, o3, 0, 0, 0);
      __builtin_amdgcn_s_setprio(0);
      short8 vb00 = *reinterpret_cast<const short8*>(vb);
      short8 vb01 = *reinterpret_cast<const short8*>(vb + 512);
      short8 vb02 = *reinterpret_cast<const short8*>(vb + 1024);
      short8 vb03 = *reinterpret_cast<const short8*>(vb + 1536);
      short8 vb10 = *reinterpret_cast<const short8*>(vb + 2048);
      short8 vb11 = *reinterpret_cast<const short8*>(vb + 2560);
      short8 vb12 = *reinterpret_cast<const short8*>(vb + 3072);
      short8 vb13 = *reinterpret_cast<const short8*>(vb + 3584);
      __builtin_amdgcn_s_setprio(1);
      o0 = __builtin_amdgcn_mfma_f32_32x32x16_bf16(fb0, vb00, o0, 0, 0, 0);
      o1 = __builtin_amdgcn_mfma_f32_32x32x16_bf16(fb0, vb01, o1, 0, 0, 0);
      o2 = __builtin_amdgcn_mfma_f32_32x32x16_bf16(fb0, vb02, o2, 0, 0, 0);
      o3 = __builtin_amdgcn_mfma_f32_32x32x16_bf16(fb0, vb03, o3, 0, 0, 0);
      o0 = __builtin_amdgcn_mfma_f32_32x32x16_bf16(fb1, vb10, o0, 0, 0, 0);
      o1 = __builtin_amdgcn_mfma_f32_32x32x16_bf16(fb1, vb11, o1, 0, 0, 0);
      o2 = __builtin_amdgcn_mfma_f32_32x32x16_bf16(fb1, vb12, o2, 0, 0, 0);
      o3 = __builtin_amdgcn_mfma_f32_32x32x16_bf16(fb1, vb13, o3, 0, 0, 0);
      __builtin_amdgcn_s_setprio(0);
    }

    __syncthreads();   // drains our stage (vmcnt) + separates K buffers
  }

  // epilogue: O rows at q' = (r&3)+8*(r>>2)+4*hi, col d = dt*32 + c
  float linv = 1.0f / l;
  #pragma unroll
  for (int r = 0; r < 16; ++r) {
    int qp_ = (r & 3) + 8 * (r >> 2) + 4 * hi;
    float li = __shfl(linv, qp_, 64);
    float* op = out + ((size_t)(row0 + qp_) * NH + h) * HD + c;
    op[0]  = o0[r] * li;
    op[32] = o1[r] * li;
    op[64] = o2[r] * li;
    op[96] = o3[r] * li;
  }
}

// ---- fallback (ws too small): direct f32 loads, single tile per iteration ----
__global__ __launch_bounds__(256, 2)
void attn_fwd_slow(const float* __restrict__ q,
                   const float* __restrict__ kp_,
                   const float* __restrict__ vp_,
                   const int* __restrict__ nseq,
                   float* __restrict__ out)
{
  const int bid  = blockIdx.x;
  const int h    = bid & (NH - 1);
  const int rb   = (T_TOK / 128 - 1) - (bid >> 5);
  const int kvh  = h / QREP;
  const int w    = threadIdx.x >> 6;
  const int lane = threadIdx.x & 63;
  const int c    = lane & 31;
  const int hi   = lane >> 5;
  const int B = *nseq, S = T_TOK / B;
  const int row0 = rb * 128 + w * 32;
  const int b = row0 / S, s0 = row0 - b * S, kb = b * S;
  const float sl2e = 0.08838834764831845f * 1.4426950408889634f;
  short8 qf[8];
  {
    const float* qp = q + ((size_t)(row0 + c) * NH + h) * HD + hi * 8;
    #pragma unroll
    for (int dc = 0; dc < 8; ++dc) {
      float4 a  = *reinterpret_cast<const float4*>(qp + dc * 16);
      float4 bq = *reinterpret_cast<const float4*>(qp + dc * 16 + 4);
      int4v wv; wv[0] = (int)pack_bf16(a.x, a.y);   wv[1] = (int)pack_bf16(a.z, a.w);
                wv[2] = (int)pack_bf16(bq.x, bq.y); wv[3] = (int)pack_bf16(bq.z, bq.w);
      qf[dc] = __builtin_bit_cast(short8, wv);
    }
  }
  f32x16 o0 = {}, o1 = {}, o2 = {}, o3 = {};
  float m = -1e30f, l = 0.0f;
  const int ntiles = s0 / 32 + 1;
  for (int t = 0; t < ntiles; ++t) {
    const int key0 = t * 32;
    const size_t koff = ((size_t)(kb + key0 + c) * NKV + kvh) * HD + hi * 8;
    const float* kp = kp_ + koff;
    f32x16 s = {};
    #pragma unroll
    for (int dc = 0; dc < 8; ++dc) {
      float4 a  = *reinterpret_cast<const float4*>(kp + dc * 16);
      float4 bk = *reinterpret_cast<const float4*>(kp + dc * 16 + 4);
      int4v wv; wv[0] = (int)pack_bf16(a.x, a.y);   wv[1] = (int)pack_bf16(a.z, a.w);
                wv[2] = (int)pack_bf16(bk.x, bk.y); wv[3] = (int)pack_bf16(bk.z, bk.w);
      short8 kf = __builtin_bit_cast(short8, wv);
      s = __builtin_amdgcn_mfma_f32_32x32x16_bf16(kf, qf[dc], s, 0, 0, 0);
    }
    if (t == ntiles - 1) {
      const int qs = s0 + c;
      #pragma unroll
      for (int r = 0; r < 16; ++r) {
        int key = key0 + (r & 3) + 8 * (r >> 2) + 4 * hi;
        if (key > qs) s[r] = -1e30f;
      }
    }
    float pm = s[0];
    #pragma unroll
    for (int r = 1; r < 16; ++r) pm = fmaxf(pm, s[r]);
    pm = fmaxf(pm, __shfl_xor(pm, 32));
    if (!__all((pm - m) * sl2e <= 8.0f)) {
      float mn = fmaxf(m, pm);
      float al = __builtin_amdgcn_exp2f(sl2e * (m - mn));
      m = mn; l *= al;
      #pragma unroll
      for (int r = 0; r < 16; ++r) {
        float ar = __shfl(al, (r & 3) + 8 * (r >> 2) + 4 * hi, 64);
        o0[r] *= ar; o1[r] *= ar; o2[r] *= ar; o3[r] *= ar;
      }
    }
    float rs = 0.0f;
    f32x16 p;
    #pragma unroll
    for (int r = 0; r < 16; ++r) {
      p[r] = __builtin_amdgcn_exp2f((s[r] - m) * sl2e);
      rs += p[r];
    }
    rs += __shfl_xor(rs, 32);
    l += rs;
    short8 f0 = p_frag(p, 0, hi), f1 = p_frag(p, 1, hi);
    #pragma unroll
    for (int st = 0; st < 2; ++st) {
      short8 pa = st ? f1 : f0;
      const size_t voff = ((size_t)(kb + key0 + 16*st + 8*hi) * NKV + kvh) * HD + c;
      const float* vp = vp_ + voff;
      float ve[8][4];
      #pragma unroll
      for (int j = 0; j < 8; ++j) {
        const float* vr = vp + (size_t)j * (NKV * HD);
        #pragma unroll
        for (int dt = 0; dt < 4; ++dt) ve[j][dt] = vr[dt * 32];
      }
      #pragma unroll
      for (int dt = 0; dt < 4; ++dt) {
        int4v vb;
        #pragma unroll
        for (int jj = 0; jj < 4; ++jj)
          vb[jj] = (int)pack_bf16(ve[2*jj][dt], ve[2*jj+1][dt]);
        short8 vfx = __builtin_bit_cast(short8, vb);
        if      (dt == 0) o0 = __builtin_amdgcn_mfma_f32_32x32x16_bf16(pa, vfx, o0, 0, 0, 0);
        else if (dt == 1) o1 = __builtin_amdgcn_mfma_f32_32x32x16_bf16(pa, vfx, o1, 0, 0, 0);
        else if (dt == 2) o2 = __builtin_amdgcn_mfma_f32_32x32x16_bf16(pa, vfx, o2, 0, 0, 0);
        else              o3 = __builtin_amdgcn_mfma_f32_32x32x16_bf16(pa, vfx, o3, 0, 0, 0);
      }
    }
  }
  float linv = 1.0f / l;
  #pragma unroll
  for (int r = 0; r < 16; ++r) {
    int qp_ = (r & 3) + 8 * (r >> 2) + 4 * hi;
    float li = __shfl(linv, qp_, 64);
    float* op = out + ((size_t)(row0 + qp_) * NH + h) * HD + c;
    op[0]  = o0[r] * li;
    op[32] = o1[r] * li;
    op[64] = o2[r] * li;
    op[96] = o3[r] * li;
  }
}

extern "C" void kernel_launch(void* const* d_in, const int* in_sizes, int n_in,
                              void* d_out, int out_size, void* d_ws, size_t ws_size,
                              hipStream_t stream) {
  const float* q = (const float*)d_in[0];
  const float* k = (const float*)d_in[1];
  const float* v = (const float*)d_in[2];
  const int* ns  = (const int*)d_in[3];
  float* o       = (float*)d_out;

  const size_t kvElems = (size_t)T_TOK * NKV * HD;  // 4,194,304 per tensor
  dim3 grid((T_TOK / 128) * NH);                    // 1024 blocks

  if (ws_size >= kvElems * 2 * sizeof(unsigned short)) {
    unsigned short* kfbuf = (unsigned short*)d_ws;
    unsigned short* vfbuf = kfbuf + kvElems;
    pack_k<<<2048, 256, 0, stream>>>(k, kfbuf, ns);
    pack_v<<<2048, 256, 0, stream>>>(v, vfbuf, ns);
    attn_fwd_fast<<<grid, dim3(256), 0, stream>>>(q, kfbuf, vfbuf, ns, o);
  } else {
    attn_fwd_slow<<<grid, dim3(256), 0, stream>>>(q, k, v, ns, o);
  }
}

// Round 20
// 75.158 us; speedup vs baseline: 1.4981x; 1.4981x over previous
//
#include <hip/hip_runtime.h>

typedef short short8 __attribute__((ext_vector_type(8)));
typedef float f32x16 __attribute__((ext_vector_type(16)));
typedef int   int4v  __attribute__((ext_vector_type(4)));
typedef int   int2v  __attribute__((ext_vector_type(2)));

#define T_TOK 4096
#define NH    32
#define NKV   8
#define HD    128
#define QREP  (NH / NKV)

__device__ __forceinline__ unsigned short f32_to_bf16_bits(float x) {
  union { float f; unsigned u; } a; a.f = x;
  unsigned r = a.u + 0x7fffu + ((a.u >> 16) & 1u);  // round-to-nearest-even
  return (unsigned short)(r >> 16);
}
__device__ __forceinline__ unsigned pack_bf16(float a, float b) {
  return (unsigned)f32_to_bf16_bits(a) | ((unsigned)f32_to_bf16_bits(b) << 16);
}
// hardware packed f32->bf16 (RNE), lo=a hi=b
__device__ __forceinline__ unsigned cvtpk(float a, float b) {
  unsigned r;
  asm("v_cvt_pk_bf16_f32 %0, %1, %2" : "=v"(r) : "v"(a), "v"(b));
  return r;
}

// async global->LDS, 16B per lane; lds dest = wave-uniform base + lane*16
__device__ __forceinline__ void stage16(const unsigned short* g, unsigned short* l) {
  __builtin_amdgcn_global_load_lds(
      (const __attribute__((address_space(1))) unsigned int*)g,
      (__attribute__((address_space(3))) unsigned int*)l,
      16, 0, 0);
}

// P (f32x16, one 32-key tile) -> bf16 A-fragment for sub-tile st (k = 8*hi + j)
__device__ __forceinline__ short8 p_frag(const f32x16& p, int st, int hi) {
  unsigned c01 = cvtpk(p[8*st+0], p[8*st+1]);
  unsigned c23 = cvtpk(p[8*st+2], p[8*st+3]);
  unsigned c45 = cvtpk(p[8*st+4], p[8*st+5]);
  unsigned c67 = cvtpk(p[8*st+6], p[8*st+7]);
  unsigned x01 = (unsigned)__shfl_xor((int)c01, 32, 64);
  unsigned x23 = (unsigned)__shfl_xor((int)c23, 32, 64);
  unsigned x45 = (unsigned)__shfl_xor((int)c45, 32, 64);
  unsigned x67 = (unsigned)__shfl_xor((int)c67, 32, 64);
  int4v pi;
  pi[0] = (int)(hi ? x45 : c01);
  pi[1] = (int)(hi ? x67 : c23);
  pi[2] = (int)(hi ? c45 : x01);
  pi[3] = (int)(hi ? c67 : x23);
  return __builtin_bit_cast(short8, pi);
}

// ---- prep A: K f32 [T][NKV][HD] -> fragment-packed bf16
__global__ __launch_bounds__(256)
void pack_k(const float* __restrict__ k, unsigned short* __restrict__ kf,
            const int* __restrict__ nseq) {
  int tid  = blockIdx.x * 256 + threadIdx.x;   // 2^19 threads
  int lane = tid & 63;
  int dc   = (tid >> 6) & 7;
  int gt   = (tid >> 9) & (T_TOK / 32 - 1);
  int kvh  = tid >> 16;
  int c = lane & 31, hi = lane >> 5;
  int token = gt * 32 + c;
  const float* src = k + ((size_t)token * NKV + kvh) * HD + dc * 16 + hi * 8;
  float4 a  = *reinterpret_cast<const float4*>(src);
  float4 b4 = *reinterpret_cast<const float4*>(src + 4);
  const int B = *nseq, S = T_TOK / B, S32 = S >> 5;
  int bseq = gt / S32, tile = gt - bseq * S32;
  size_t off = ((size_t)(bseq * NKV + kvh) * S32 + tile) * 4096 + dc * 512 + lane * 8;
  int4v wv; wv[0] = (int)pack_bf16(a.x, a.y);   wv[1] = (int)pack_bf16(a.z, a.w);
            wv[2] = (int)pack_bf16(b4.x, b4.y); wv[3] = (int)pack_bf16(b4.z, b4.w);
  *reinterpret_cast<int4v*>(kf + off) = wv;
}

// ---- prep B: V f32 [T][NKV][HD] -> fragment-packed bf16 (PV B-operand order)
__global__ __launch_bounds__(256)
void pack_v(const float* __restrict__ v, unsigned short* __restrict__ vf,
            const int* __restrict__ nseq) {
  int tid  = blockIdx.x * 256 + threadIdx.x;
  int lane = tid & 63;
  int idx  = (tid >> 6) & 7;                   // st*4 + dt
  int gt   = (tid >> 9) & (T_TOK / 32 - 1);
  int kvh  = tid >> 16;
  int c = lane & 31, hi = lane >> 5;
  int st = idx >> 2, dt = idx & 3;
  int token0 = gt * 32 + 16 * st + 8 * hi;
  const float* src = v + ((size_t)token0 * NKV + kvh) * HD + dt * 32 + c;
  unsigned u[4];
  #pragma unroll
  for (int jj = 0; jj < 4; ++jj) {
    float a = src[(size_t)(2 * jj)     * (NKV * HD)];
    float b = src[(size_t)(2 * jj + 1) * (NKV * HD)];
    u[jj] = pack_bf16(a, b);
  }
  const int B = *nseq, S = T_TOK / B, S32 = S >> 5;
  int bseq = gt / S32, tile = gt - bseq * S32;
  size_t off = ((size_t)(bseq * NKV + kvh) * S32 + tile) * 4096 + idx * 512 + lane * 8;
  int4v wv; wv[0] = (int)u[0]; wv[1] = (int)u[1]; wv[2] = (int)u[2]; wv[3] = (int)u[3];
  *reinterpret_cast<int4v*>(vf + off) = wv;
}

// ---- main kernel: K LDS dbuf (32KB), V direct, XCD-pinned kvh (T1) ----
__global__ __launch_bounds__(256, 3)
void attn_fwd_fast(const float* __restrict__ q,
                   const unsigned short* __restrict__ kfp,
                   const unsigned short* __restrict__ vfp,
                   const int* __restrict__ nseq,
                   float* __restrict__ out)
{
  __shared__ __align__(16) unsigned short sm[16384];   // 32 KB

  const int bid  = blockIdx.x;
  // XCD-pinning remap (bijective, 1024 % 8 == 0): XCD (= bid&7) <- kvh.
  // All 128 blocks of one kvh share one XCD-L2 -> aligned V scans hit L2.
  const int vid  = (bid & 7) * 128 + (bid >> 3);
  const int kvh  = vid >> 7;
  const int rem  = vid & 127;
  const int z    = rem >> 2;              // row-slot 0..31, ascending with bid
  const int h    = kvh * QREP + (rem & 3);
  const int w    = threadIdx.x >> 6;
  const int lane = threadIdx.x & 63;
  const int c    = lane & 31;
  const int hi   = lane >> 5;

  const int B = *nseq;
  const int S = T_TOK / B;
  const int S32 = S >> 5;
  const int RBS = S >> 7;                 // 128-row blocks per sequence

  // longest-first: rloc descending with dispatch order, then sequence
  const int rloc = RBS - 1 - (z / B);
  const int seq  = z - (z / B) * B;
  const int rb   = seq * RBS + rloc;

  const int rbase = rb * 128;
  const int row0  = rbase + w * 32;
  const int s0    = row0 - seq * S;
  const int ntw   = s0 / 32 + 1;
  const int diag  = ntw - 1;
  const int npb   = (rloc * 4 + 4) >> 1;  // K-pair count

  const float sl2e = 0.08838834764831845f * 1.4426950408889634f;

  const unsigned short* kf_blk = kfp + ((size_t)(seq * NKV + kvh) * S32) * 4096;
  const unsigned short* vfb = vfp + ((size_t)(seq * NKV + kvh) * S32) * 4096 + lane * 8;

  // ---- Q startup: f32 coalesced -> bf16 swizzled tile using the whole 32KB ----
  char* qlds = (char*)sm;
  {
    #pragma unroll
    for (int j = 0; j < 16; ++j) {
      const int rowb = w * 32 + 2 * j + hi;
      const float* gsrc = q + ((size_t)(rbase + rowb) * NH + h) * HD + 4 * c;
      float4 a = *reinterpret_cast<const float4*>(gsrc);
      int2v u;
      u[0] = (int)cvtpk(a.x * sl2e, a.y * sl2e);
      u[1] = (int)cvtpk(a.z * sl2e, a.w * sl2e);
      const int off = (rowb * 256 + 8 * c) ^ ((rowb & 7) << 4);
      *reinterpret_cast<int2v*>(qlds + off) = u;
    }
  }
  __syncthreads();

  short8 qf[8];
  {
    const int rowb = w * 32 + c;
    #pragma unroll
    for (int dc = 0; dc < 8; ++dc) {
      const int off = (rowb * 256 + dc * 32 + hi * 16) ^ ((c & 7) << 4);
      qf[dc] = *reinterpret_cast<const short8*>(qlds + off);
    }
  }
  __syncthreads();   // all Q reads done before K staging overwrites

  // ---- prologue: stage K pair 0 into buf0 (sm[0..8192)) ----
  {
    const unsigned short* src = kf_blk + (size_t)(w >> 1) * 4096 + (w & 1) * 2048 + lane * 8;
    unsigned short* dst = sm + w * 2048;
    #pragma unroll
    for (int j = 0; j < 4; ++j) stage16(src + j * 512, dst + j * 512);
  }
  __syncthreads();

  f32x16 o0 = {}, o1 = {}, o2 = {}, o3 = {};
  float m = -1e30f, l = 0.0f;

  for (int i = 0; i < npb; ++i) {
    const unsigned short* curK = sm + (i & 1) * 8192;

    if (i + 1 < npb) {   // stage next K pair into other buffer
      const unsigned short* src =
          kf_blk + (size_t)(2 * (i + 1) + (w >> 1)) * 4096 + (w & 1) * 2048 + lane * 8;
      unsigned short* dst = sm + ((i + 1) & 1) * 8192 + w * 2048;
      #pragma unroll
      for (int j = 0; j < 4; ++j) stage16(src + j * 512, dst + j * 512);
    }

    if (2 * i < ntw) {   // wave-uniform: this wave still has work
      const int ta = 2 * i, tb = 2 * i + 1;
      const unsigned short* kA = curK + lane * 8;
      const unsigned short* kB = curK + 4096 + lane * 8;

      f32x16 sa = {}, sb = {};
      __builtin_amdgcn_s_setprio(1);
      #pragma unroll
      for (int dc = 0; dc < 8; ++dc) {
        short8 ka  = *reinterpret_cast<const short8*>(kA + dc * 512);
        short8 kb8 = *reinterpret_cast<const short8*>(kB + dc * 512);
        sa = __builtin_amdgcn_mfma_f32_32x32x16_bf16(ka,  qf[dc], sa, 0, 0, 0);
        sb = __builtin_amdgcn_mfma_f32_32x32x16_bf16(kb8, qf[dc], sb, 0, 0, 0);
      }
      __builtin_amdgcn_s_setprio(0);

      const int qs = s0 + c;
      if (tb >= diag) {
        #pragma unroll
        for (int r = 0; r < 16; ++r) {
          int key = tb * 32 + (r & 3) + 8 * (r >> 2) + 4 * hi;
          if (key > qs) sb[r] = -1e30f;
        }
      }
      if (ta >= diag) {
        #pragma unroll
        for (int r = 0; r < 16; ++r) {
          int key = ta * 32 + (r & 3) + 8 * (r >> 2) + 4 * hi;
          if (key > qs) sa[r] = -1e30f;
        }
      }

      float pm = fmaxf(sa[0], sb[0]);
      #pragma unroll
      for (int r = 1; r < 16; ++r) pm = fmaxf(pm, fmaxf(sa[r], sb[r]));
      pm = fmaxf(pm, __shfl_xor(pm, 32));

      if (!__all(pm - m <= 8.0f)) {   // T13 defer-max (log2 domain)
        float mn = fmaxf(m, pm);
        float al = __builtin_amdgcn_exp2f(m - mn);
        m = mn;
        l *= al;
        #pragma unroll
        for (int r = 0; r < 16; ++r) {
          float ar = __shfl(al, (r & 3) + 8 * (r >> 2) + 4 * hi, 64);
          o0[r] *= ar; o1[r] *= ar; o2[r] *= ar; o3[r] *= ar;
        }
      }

      float rs = 0.0f;
      f32x16 pA, pB;
      #pragma unroll
      for (int r = 0; r < 16; ++r) {
        pA[r] = __builtin_amdgcn_exp2f(sa[r] - m);
        pB[r] = __builtin_amdgcn_exp2f(sb[r] - m);
        rs += pA[r] + pB[r];
      }
      rs += __shfl_xor(rs, 32);
      l += rs;

      short8 fa0 = p_frag(pA, 0, hi), fa1 = p_frag(pA, 1, hi);
      short8 fb0 = p_frag(pB, 0, hi), fb1 = p_frag(pB, 1, hi);

      // V fragments direct from packed global (coalesced 1KB/instr, L2-pinned)
      const unsigned short* va = vfb + (size_t)ta * 4096;
      const unsigned short* vb = vfb + (size_t)tb * 4096;
      short8 va00 = *reinterpret_cast<const short8*>(va);
      short8 va01 = *reinterpret_cast<const short8*>(va + 512);
      short8 va02 = *reinterpret_cast<const short8*>(va + 1024);
      short8 va03 = *reinterpret_cast<const short8*>(va + 1536);
      short8 va10 = *reinterpret_cast<const short8*>(va + 2048);
      short8 va11 = *reinterpret_cast<const short8*>(va + 2560);
      short8 va12 = *reinterpret_cast<const short8*>(va + 3072);
      short8 va13 = *reinterpret_cast<const short8*>(va + 3584);
      __builtin_amdgcn_s_setprio(1);
      o0 = __builtin_amdgcn_mfma_f32_32x32x16_bf16(fa0, va00, o0, 0, 0, 0);
      o1 = __builtin_amdgcn_mfma_f32_32x32x16_bf16(fa0, va01, o1, 0, 0, 0);
      o2 = __builtin_amdgcn_mfma_f32_32x32x16_bf16(fa0, va02, o2, 0, 0, 0);
      o3 = __builtin_amdgcn_mfma_f32_32x32x16_bf16(fa0, va03, o3, 0, 0, 0);
      o0 = __builtin_amdgcn_mfma_f32_32x32x16_bf16(fa1, va10, o0, 0, 0, 0);
      o1 = __builtin_amdgcn_mfma_f32_32x32x16_bf16(fa1, va11, o1, 0, 0, 0);
      o2 = __builtin_amdgcn_mfma_f32_32x32x16_bf16(fa1, va12, o2, 0, 0, 0);
      o3 = __builtin_amdgcn_mfma_f32_32x32x16_bf16(fa1, va13, o3, 0, 0, 0);
      __builtin_amdgcn_s_setprio(0);
      short8 vb00 = *reinterpret_cast<const short8*>(vb);
      short8 vb01 = *reinterpret_cast<const short8*>(vb + 512);
      short8 vb02 = *reinterpret_cast<const short8*>(vb + 1024);
      short8 vb03 = *reinterpret_cast<const short8*>(vb + 1536);
      short8 vb10 = *reinterpret_cast<const short8*>(vb + 2048);
      short8 vb11 = *reinterpret_cast<const short8*>(vb + 2560);
      short8 vb12 = *reinterpret_cast<const short8*>(vb + 3072);
      short8 vb13 = *reinterpret_cast<const short8*>(vb + 3584);
      __builtin_amdgcn_s_setprio(1);
      o0 = __builtin_amdgcn_mfma_f32_32x32x16_bf16(fb0, vb00, o0, 0, 0, 0);
      o1 = __builtin_amdgcn_mfma_f32_32x32x16_bf16(fb0, vb01, o1, 0, 0, 0);
      o2 = __builtin_amdgcn_mfma_f32_32x32x16_bf16(fb0, vb02, o2, 0, 0, 0);
      o3 = __builtin_amdgcn_mfma_f32_32x32x16_bf16(fb0, vb03, o3, 0, 0, 0);
      o0 = __builtin_amdgcn_mfma_f32_32x32x16_bf16(fb1, vb10, o0, 0, 0, 0);
      o1 = __builtin_amdgcn_mfma_f32_32x32x16_bf16(fb1, vb11, o1, 0, 0, 0);
      o2 = __builtin_amdgcn_mfma_f32_32x32x16_bf16(fb1, vb12, o2, 0, 0, 0);
      o3 = __builtin_amdgcn_mfma_f32_32x32x16_bf16(fb1, vb13, o3, 0, 0, 0);
      __builtin_amdgcn_s_setprio(0);
    }

    __syncthreads();   // drains our stage (vmcnt) + separates K buffers
  }

  // epilogue: O rows at q' = (r&3)+8*(r>>2)+4*hi, col d = dt*32 + c
  float linv = 1.0f / l;
  #pragma unroll
  for (int r = 0; r < 16; ++r) {
    int qp_ = (r & 3) + 8 * (r >> 2) + 4 * hi;
    float li = __shfl(linv, qp_, 64);
    float* op = out + ((size_t)(row0 + qp_) * NH + h) * HD + c;
    op[0]  = o0[r] * li;
    op[32] = o1[r] * li;
    op[64] = o2[r] * li;
    op[96] = o3[r] * li;
  }
}

// ---- fallback (ws too small): direct f32 loads, single tile per iteration ----
__global__ __launch_bounds__(256, 2)
void attn_fwd_slow(const float* __restrict__ q,
                   const float* __restrict__ kp_,
                   const float* __restrict__ vp_,
                   const int* __restrict__ nseq,
                   float* __restrict__ out)
{
  const int bid  = blockIdx.x;
  const int h    = bid & (NH - 1);
  const int rb   = (T_TOK / 128 - 1) - (bid >> 5);
  const int kvh  = h / QREP;
  const int w    = threadIdx.x >> 6;
  const int lane = threadIdx.x & 63;
  const int c    = lane & 31;
  const int hi   = lane >> 5;
  const int B = *nseq, S = T_TOK / B;
  const int row0 = rb * 128 + w * 32;
  const int b = row0 / S, s0 = row0 - b * S, kb = b * S;
  const float sl2e = 0.08838834764831845f * 1.4426950408889634f;
  short8 qf[8];
  {
    const float* qp = q + ((size_t)(row0 + c) * NH + h) * HD + hi * 8;
    #pragma unroll
    for (int dc = 0; dc < 8; ++dc) {
      float4 a  = *reinterpret_cast<const float4*>(qp + dc * 16);
      float4 bq = *reinterpret_cast<const float4*>(qp + dc * 16 + 4);
      int4v wv; wv[0] = (int)pack_bf16(a.x, a.y);   wv[1] = (int)pack_bf16(a.z, a.w);
                wv[2] = (int)pack_bf16(bq.x, bq.y); wv[3] = (int)pack_bf16(bq.z, bq.w);
      qf[dc] = __builtin_bit_cast(short8, wv);
    }
  }
  f32x16 o0 = {}, o1 = {}, o2 = {}, o3 = {};
  float m = -1e30f, l = 0.0f;
  const int ntiles = s0 / 32 + 1;
  for (int t = 0; t < ntiles; ++t) {
    const int key0 = t * 32;
    const size_t koff = ((size_t)(kb + key0 + c) * NKV + kvh) * HD + hi * 8;
    const float* kp = kp_ + koff;
    f32x16 s = {};
    #pragma unroll
    for (int dc = 0; dc < 8; ++dc) {
      float4 a  = *reinterpret_cast<const float4*>(kp + dc * 16);
      float4 bk = *reinterpret_cast<const float4*>(kp + dc * 16 + 4);
      int4v wv; wv[0] = (int)pack_bf16(a.x, a.y);   wv[1] = (int)pack_bf16(a.z, a.w);
                wv[2] = (int)pack_bf16(bk.x, bk.y); wv[3] = (int)pack_bf16(bk.z, bk.w);
      short8 kf = __builtin_bit_cast(short8, wv);
      s = __builtin_amdgcn_mfma_f32_32x32x16_bf16(kf, qf[dc], s, 0, 0, 0);
    }
    if (t == ntiles - 1) {
      const int qs = s0 + c;
      #pragma unroll
      for (int r = 0; r < 16; ++r) {
        int key = key0 + (r & 3) + 8 * (r >> 2) + 4 * hi;
        if (key > qs) s[r] = -1e30f;
      }
    }
    float pm = s[0];
    #pragma unroll
    for (int r = 1; r < 16; ++r) pm = fmaxf(pm, s[r]);
    pm = fmaxf(pm, __shfl_xor(pm, 32));
    if (!__all((pm - m) * sl2e <= 8.0f)) {
      float mn = fmaxf(m, pm);
      float al = __builtin_amdgcn_exp2f(sl2e * (m - mn));
      m = mn; l *= al;
      #pragma unroll
      for (int r = 0; r < 16; ++r) {
        float ar = __shfl(al, (r & 3) + 8 * (r >> 2) + 4 * hi, 64);
        o0[r] *= ar; o1[r] *= ar; o2[r] *= ar; o3[r] *= ar;
      }
    }
    float rs = 0.0f;
    f32x16 p;
    #pragma unroll
    for (int r = 0; r < 16; ++r) {
      p[r] = __builtin_amdgcn_exp2f((s[r] - m) * sl2e);
      rs += p[r];
    }
    rs += __shfl_xor(rs, 32);
    l += rs;
    short8 f0 = p_frag(p, 0, hi), f1 = p_frag(p, 1, hi);
    #pragma unroll
    for (int st = 0; st < 2; ++st) {
      short8 pa = st ? f1 : f0;
      const size_t voff = ((size_t)(kb + key0 + 16*st + 8*hi) * NKV + kvh) * HD + c;
      const float* vp = vp_ + voff;
      float ve[8][4];
      #pragma unroll
      for (int j = 0; j < 8; ++j) {
        const float* vr = vp + (size_t)j * (NKV * HD);
        #pragma unroll
        for (int dt = 0; dt < 4; ++dt) ve[j][dt] = vr[dt * 32];
      }
      #pragma unroll
      for (int dt = 0; dt < 4; ++dt) {
        int4v vb;
        #pragma unroll
        for (int jj = 0; jj < 4; ++jj)
          vb[jj] = (int)pack_bf16(ve[2*jj][dt], ve[2*jj+1][dt]);
        short8 vfx = __builtin_bit_cast(short8, vb);
        if      (dt == 0) o0 = __builtin_amdgcn_mfma_f32_32x32x16_bf16(pa, vfx, o0, 0, 0, 0);
        else if (dt == 1) o1 = __builtin_amdgcn_mfma_f32_32x32x16_bf16(pa, vfx, o1, 0, 0, 0);
        else if (dt == 2) o2 = __builtin_amdgcn_mfma_f32_32x32x16_bf16(pa, vfx, o2, 0, 0, 0);
        else              o3 = __builtin_amdgcn_mfma_f32_32x32x16_bf16(pa, vfx, o3, 0, 0, 0);
      }
    }
  }
  float linv = 1.0f / l;
  #pragma unroll
  for (int r = 0; r < 16; ++r) {
    int qp_ = (r & 3) + 8 * (r >> 2) + 4 * hi;
    float li = __shfl(linv, qp_, 64);
    float* op = out + ((size_t)(row0 + qp_) * NH + h) * HD + c;
    op[0]  = o0[r] * li;
    op[32] = o1[r] * li;
    op[64] = o2[r] * li;
    op[96] = o3[r] * li;
  }
}

extern "C" void kernel_launch(void* const* d_in, const int* in_sizes, int n_in,
                              void* d_out, int out_size, void* d_ws, size_t ws_size,
                              hipStream_t stream) {
  const float* q = (const float*)d_in[0];
  const float* k = (const float*)d_in[1];
  const float* v = (const float*)d_in[2];
  const int* ns  = (const int*)d_in[3];
  float* o       = (float*)d_out;

  const size_t kvElems = (size_t)T_TOK * NKV * HD;  // 4,194,304 per tensor
  dim3 grid((T_TOK / 128) * NH);                    // 1024 blocks

  if (ws_size >= kvElems * 2 * sizeof(unsigned short)) {
    unsigned short* kfbuf = (unsigned short*)d_ws;
    unsigned short* vfbuf = kfbuf + kvElems;
    pack_k<<<2048, 256, 0, stream>>>(k, kfbuf, ns);
    pack_v<<<2048, 256, 0, stream>>>(v, vfbuf, ns);
    attn_fwd_fast<<<grid, dim3(256), 0, stream>>>(q, kfbuf, vfbuf, ns, o);
  } else {
    attn_fwd_slow<<<grid, dim3(256), 0, stream>>>(q, k, v, ns, o);
  }
}

// Round 21
// 74.987 us; speedup vs baseline: 1.5015x; 1.0023x over previous
//
#include <hip/hip_runtime.h>

typedef short short8 __attribute__((ext_vector_type(8)));
typedef float f32x16 __attribute__((ext_vector_type(16)));
typedef int   int4v  __attribute__((ext_vector_type(4)));
typedef int   int2v  __attribute__((ext_vector_type(2)));

#define T_TOK 4096
#define NH    32
#define NKV   8
#define HD    128
#define QREP  (NH / NKV)

__device__ __forceinline__ unsigned short f32_to_bf16_bits(float x) {
  union { float f; unsigned u; } a; a.f = x;
  unsigned r = a.u + 0x7fffu + ((a.u >> 16) & 1u);  // round-to-nearest-even
  return (unsigned short)(r >> 16);
}
__device__ __forceinline__ unsigned pack_bf16(float a, float b) {
  return (unsigned)f32_to_bf16_bits(a) | ((unsigned)f32_to_bf16_bits(b) << 16);
}
// hardware packed f32->bf16 (RNE), lo=a hi=b
__device__ __forceinline__ unsigned cvtpk(float a, float b) {
  unsigned r;
  asm("v_cvt_pk_bf16_f32 %0, %1, %2" : "=v"(r) : "v"(a), "v"(b));
  return r;
}

// async global->LDS, 16B per lane; lds dest = wave-uniform base + lane*16
__device__ __forceinline__ void stage16(const unsigned short* g, unsigned short* l) {
  __builtin_amdgcn_global_load_lds(
      (const __attribute__((address_space(1))) unsigned int*)g,
      (__attribute__((address_space(3))) unsigned int*)l,
      16, 0, 0);
}

// P (f32x16, one 32-key tile) -> bf16 A-fragment for sub-tile st (k = 8*hi + j)
__device__ __forceinline__ short8 p_frag(const f32x16& p, int st, int hi) {
  unsigned c01 = cvtpk(p[8*st+0], p[8*st+1]);
  unsigned c23 = cvtpk(p[8*st+2], p[8*st+3]);
  unsigned c45 = cvtpk(p[8*st+4], p[8*st+5]);
  unsigned c67 = cvtpk(p[8*st+6], p[8*st+7]);
  unsigned x01 = (unsigned)__shfl_xor((int)c01, 32, 64);
  unsigned x23 = (unsigned)__shfl_xor((int)c23, 32, 64);
  unsigned x45 = (unsigned)__shfl_xor((int)c45, 32, 64);
  unsigned x67 = (unsigned)__shfl_xor((int)c67, 32, 64);
  int4v pi;
  pi[0] = (int)(hi ? x45 : c01);
  pi[1] = (int)(hi ? x67 : c23);
  pi[2] = (int)(hi ? c45 : x01);
  pi[3] = (int)(hi ? c67 : x23);
  return __builtin_bit_cast(short8, pi);
}

// ---- prep v2: coalesced slab read -> swizzled LDS -> fragment-packed writes ----
// blocks [0,T/32): K groups; [T/32, 2*T/32): V groups. 256 threads.
// Produces layouts bit-identical to the original pack_k / pack_v.
__global__ __launch_bounds__(256)
void pack_kv2(const float* __restrict__ kg, const float* __restrict__ vg,
              unsigned short* __restrict__ kf, unsigned short* __restrict__ vf,
              const int* __restrict__ nseq) {
  __shared__ __align__(16) unsigned short slab[32768];  // 64KB: [32 tok][8 kvh][128 d], XOR-swizzled
  const int B = *nseq, S = T_TOK / B, S32 = S >> 5;
  const int NG = T_TOK / 32;                  // 128 token-groups
  const bool isV = blockIdx.x >= NG;
  const int g = isV ? blockIdx.x - NG : blockIdx.x;
  const float* src = (isV ? vg : kg) + (size_t)g * 32 * (NKV * HD);
  const int tid = threadIdx.x;

  // step 1: fully-coalesced read, convert, swizzled LDS store (8B/thread/iter)
  #pragma unroll
  for (int it = 0; it < 32; ++it) {
    int fi = it * 1024 + tid * 4;             // float index within slab (32768 floats)
    float4 a = *reinterpret_cast<const float4*>(src + fi);
    int2v u;
    u[0] = (int)pack_bf16(a.x, a.y);
    u[1] = (int)pack_bf16(a.z, a.w);
    int tok = fi >> 10;                       // 1024 floats per token
    int byteoff = (fi * 2) ^ ((tok & 7) << 4);
    *reinterpret_cast<int2v*>((char*)slab + byteoff) = u;
  }
  __syncthreads();

  const int bseq = g / S32, tile = g - bseq * S32;
  if (!isV) {
    // K: out[dc*512 + lane*8 + j] = slab[tok=c][kvh][dc*16 + hi*8 + j]
    for (int kvh = 0; kvh < NKV; ++kvh) {
      unsigned short* dst = kf + ((size_t)(bseq * NKV + kvh) * S32 + tile) * 4096;
      #pragma unroll
      for (int it = 0; it < 2; ++it) {
        int n = it * 256 + tid;               // 16B slot: dc*64 + lane
        int dc = n >> 6, lane = n & 63;
        int c = lane & 31, hi = lane >> 5;
        int byteoff = (c * 2048 + kvh * 256 + (dc * 16 + hi * 8) * 2) ^ ((c & 7) << 4);
        int4v v4 = *reinterpret_cast<const int4v*>((char*)slab + byteoff);
        *reinterpret_cast<int4v*>(dst + (size_t)n * 8) = v4;
      }
    }
  } else {
    // V: slot m = kvh*512 + idx*64 + lane; j-th short = slab[16st+8hi+j][kvh][dt*32+c]
    #pragma unroll
    for (int it = 0; it < 16; ++it) {
      int mm = it * 256 + tid;                // 4096 slots of 16B total
      int kvh = mm >> 9, rem = mm & 511;
      int idx = rem >> 6, lane = rem & 63;
      int st = idx >> 2, dt = idx & 3;
      int c = lane & 31, hi = lane >> 5;
      unsigned u[4];
      #pragma unroll
      for (int jj = 0; jj < 4; ++jj) {
        int t0 = 16 * st + 8 * hi + 2 * jj;
        int t1 = t0 + 1;
        int b0 = (t0 * 2048 + kvh * 256 + (dt * 32 + c) * 2) ^ ((t0 & 7) << 4);
        int b1 = (t1 * 2048 + kvh * 256 + (dt * 32 + c) * 2) ^ ((t1 & 7) << 4);
        unsigned short s0v = *reinterpret_cast<const unsigned short*>((char*)slab + b0);
        unsigned short s1v = *reinterpret_cast<const unsigned short*>((char*)slab + b1);
        u[jj] = (unsigned)s0v | ((unsigned)s1v << 16);
      }
      unsigned short* dst = vf + ((size_t)(bseq * NKV + kvh) * S32 + tile) * 4096;
      int4v wv; wv[0] = (int)u[0]; wv[1] = (int)u[1]; wv[2] = (int)u[2]; wv[3] = (int)u[3];
      *reinterpret_cast<int4v*>(dst + (size_t)(idx * 512 + lane * 8)) = wv;
    }
  }
}

// ---- main kernel: K LDS dbuf (32KB), V direct, XCD-pinned kvh (T1) ----
// (byte-identical to the verified 75.2us round-20 kernel)
__global__ __launch_bounds__(256, 3)
void attn_fwd_fast(const float* __restrict__ q,
                   const unsigned short* __restrict__ kfp,
                   const unsigned short* __restrict__ vfp,
                   const int* __restrict__ nseq,
                   float* __restrict__ out)
{
  __shared__ __align__(16) unsigned short sm[16384];   // 32 KB

  const int bid  = blockIdx.x;
  // XCD-pinning remap (bijective, 1024 % 8 == 0): XCD (= bid&7) <- kvh.
  const int vid  = (bid & 7) * 128 + (bid >> 3);
  const int kvh  = vid >> 7;
  const int rem  = vid & 127;
  const int z    = rem >> 2;              // row-slot 0..31, ascending with bid
  const int h    = kvh * QREP + (rem & 3);
  const int w    = threadIdx.x >> 6;
  const int lane = threadIdx.x & 63;
  const int c    = lane & 31;
  const int hi   = lane >> 5;

  const int B = *nseq;
  const int S = T_TOK / B;
  const int S32 = S >> 5;
  const int RBS = S >> 7;                 // 128-row blocks per sequence

  // longest-first: rloc descending with dispatch order, then sequence
  const int rloc = RBS - 1 - (z / B);
  const int seq  = z - (z / B) * B;
  const int rb   = seq * RBS + rloc;

  const int rbase = rb * 128;
  const int row0  = rbase + w * 32;
  const int s0    = row0 - seq * S;
  const int ntw   = s0 / 32 + 1;
  const int diag  = ntw - 1;
  const int npb   = (rloc * 4 + 4) >> 1;  // K-pair count

  const float sl2e = 0.08838834764831845f * 1.4426950408889634f;

  const unsigned short* kf_blk = kfp + ((size_t)(seq * NKV + kvh) * S32) * 4096;
  const unsigned short* vfb = vfp + ((size_t)(seq * NKV + kvh) * S32) * 4096 + lane * 8;

  // ---- Q startup: f32 coalesced -> bf16 swizzled tile using the whole 32KB ----
  char* qlds = (char*)sm;
  {
    #pragma unroll
    for (int j = 0; j < 16; ++j) {
      const int rowb = w * 32 + 2 * j + hi;
      const float* gsrc = q + ((size_t)(rbase + rowb) * NH + h) * HD + 4 * c;
      float4 a = *reinterpret_cast<const float4*>(gsrc);
      int2v u;
      u[0] = (int)cvtpk(a.x * sl2e, a.y * sl2e);
      u[1] = (int)cvtpk(a.z * sl2e, a.w * sl2e);
      const int off = (rowb * 256 + 8 * c) ^ ((rowb & 7) << 4);
      *reinterpret_cast<int2v*>(qlds + off) = u;
    }
  }
  __syncthreads();

  short8 qf[8];
  {
    const int rowb = w * 32 + c;
    #pragma unroll
    for (int dc = 0; dc < 8; ++dc) {
      const int off = (rowb * 256 + dc * 32 + hi * 16) ^ ((c & 7) << 4);
      qf[dc] = *reinterpret_cast<const short8*>(qlds + off);
    }
  }
  __syncthreads();   // all Q reads done before K staging overwrites

  // ---- prologue: stage K pair 0 into buf0 (sm[0..8192)) ----
  {
    const unsigned short* src = kf_blk + (size_t)(w >> 1) * 4096 + (w & 1) * 2048 + lane * 8;
    unsigned short* dst = sm + w * 2048;
    #pragma unroll
    for (int j = 0; j < 4; ++j) stage16(src + j * 512, dst + j * 512);
  }
  __syncthreads();

  f32x16 o0 = {}, o1 = {}, o2 = {}, o3 = {};
  float m = -1e30f, l = 0.0f;

  for (int i = 0; i < npb; ++i) {
    const unsigned short* curK = sm + (i & 1) * 8192;

    if (i + 1 < npb) {   // stage next K pair into other buffer
      const unsigned short* src =
          kf_blk + (size_t)(2 * (i + 1) + (w >> 1)) * 4096 + (w & 1) * 2048 + lane * 8;
      unsigned short* dst = sm + ((i + 1) & 1) * 8192 + w * 2048;
      #pragma unroll
      for (int j = 0; j < 4; ++j) stage16(src + j * 512, dst + j * 512);
    }

    if (2 * i < ntw) {   // wave-uniform: this wave still has work
      const int ta = 2 * i, tb = 2 * i + 1;
      const unsigned short* kA = curK + lane * 8;
      const unsigned short* kB = curK + 4096 + lane * 8;

      f32x16 sa = {}, sb = {};
      __builtin_amdgcn_s_setprio(1);
      #pragma unroll
      for (int dc = 0; dc < 8; ++dc) {
        short8 ka  = *reinterpret_cast<const short8*>(kA + dc * 512);
        short8 kb8 = *reinterpret_cast<const short8*>(kB + dc * 512);
        sa = __builtin_amdgcn_mfma_f32_32x32x16_bf16(ka,  qf[dc], sa, 0, 0, 0);
        sb = __builtin_amdgcn_mfma_f32_32x32x16_bf16(kb8, qf[dc], sb, 0, 0, 0);
      }
      __builtin_amdgcn_s_setprio(0);

      const int qs = s0 + c;
      if (tb >= diag) {
        #pragma unroll
        for (int r = 0; r < 16; ++r) {
          int key = tb * 32 + (r & 3) + 8 * (r >> 2) + 4 * hi;
          if (key > qs) sb[r] = -1e30f;
        }
      }
      if (ta >= diag) {
        #pragma unroll
        for (int r = 0; r < 16; ++r) {
          int key = ta * 32 + (r & 3) + 8 * (r >> 2) + 4 * hi;
          if (key > qs) sa[r] = -1e30f;
        }
      }

      float pm = fmaxf(sa[0], sb[0]);
      #pragma unroll
      for (int r = 1; r < 16; ++r) pm = fmaxf(pm, fmaxf(sa[r], sb[r]));
      pm = fmaxf(pm, __shfl_xor(pm, 32));

      if (!__all(pm - m <= 8.0f)) {   // T13 defer-max (log2 domain)
        float mn = fmaxf(m, pm);
        float al = __builtin_amdgcn_exp2f(m - mn);
        m = mn;
        l *= al;
        #pragma unroll
        for (int r = 0; r < 16; ++r) {
          float ar = __shfl(al, (r & 3) + 8 * (r >> 2) + 4 * hi, 64);
          o0[r] *= ar; o1[r] *= ar; o2[r] *= ar; o3[r] *= ar;
        }
      }

      float rs = 0.0f;
      f32x16 pA, pB;
      #pragma unroll
      for (int r = 0; r < 16; ++r) {
        pA[r] = __builtin_amdgcn_exp2f(sa[r] - m);
        pB[r] = __builtin_amdgcn_exp2f(sb[r] - m);
        rs += pA[r] + pB[r];
      }
      rs += __shfl_xor(rs, 32);
      l += rs;

      short8 fa0 = p_frag(pA, 0, hi), fa1 = p_frag(pA, 1, hi);
      short8 fb0 = p_frag(pB, 0, hi), fb1 = p_frag(pB, 1, hi);

      // V fragments direct from packed global (coalesced 1KB/instr, L2-pinned)
      const unsigned short* va = vfb + (size_t)ta * 4096;
      const unsigned short* vb = vfb + (size_t)tb * 4096;
      short8 va00 = *reinterpret_cast<const short8*>(va);
      short8 va01 = *reinterpret_cast<const short8*>(va + 512);
      short8 va02 = *reinterpret_cast<const short8*>(va + 1024);
      short8 va03 = *reinterpret_cast<const short8*>(va + 1536);
      short8 va10 = *reinterpret_cast<const short8*>(va + 2048);
      short8 va11 = *reinterpret_cast<const short8*>(va + 2560);
      short8 va12 = *reinterpret_cast<const short8*>(va + 3072);
      short8 va13 = *reinterpret_cast<const short8*>(va + 3584);
      __builtin_amdgcn_s_setprio(1);
      o0 = __builtin_amdgcn_mfma_f32_32x32x16_bf16(fa0, va00, o0, 0, 0, 0);
      o1 = __builtin_amdgcn_mfma_f32_32x32x16_bf16(fa0, va01, o1, 0, 0, 0);
      o2 = __builtin_amdgcn_mfma_f32_32x32x16_bf16(fa0, va02, o2, 0, 0, 0);
      o3 = __builtin_amdgcn_mfma_f32_32x32x16_bf16(fa0, va03, o3, 0, 0, 0);
      o0 = __builtin_amdgcn_mfma_f32_32x32x16_bf16(fa1, va10, o0, 0, 0, 0);
      o1 = __builtin_amdgcn_mfma_f32_32x32x16_bf16(fa1, va11, o1, 0, 0, 0);
      o2 = __builtin_amdgcn_mfma_f32_32x32x16_bf16(fa1, va12, o2, 0, 0, 0);
      o3 = __builtin_amdgcn_mfma_f32_32x32x16_bf16(fa1, va13, o3, 0, 0, 0);
      __builtin_amdgcn_s_setprio(0);
      short8 vb00 = *reinterpret_cast<const short8*>(vb);
      short8 vb01 = *reinterpret_cast<const short8*>(vb + 512);
      short8 vb02 = *reinterpret_cast<const short8*>(vb + 1024);
      short8 vb03 = *reinterpret_cast<const short8*>(vb + 1536);
      short8 vb10 = *reinterpret_cast<const short8*>(vb + 2048);
      short8 vb11 = *reinterpret_cast<const short8*>(vb + 2560);
      short8 vb12 = *reinterpret_cast<const short8*>(vb + 3072);
      short8 vb13 = *reinterpret_cast<const short8*>(vb + 3584);
      __builtin_amdgcn_s_setprio(1);
      o0 = __builtin_amdgcn_mfma_f32_32x32x16_bf16(fb0, vb00, o0, 0, 0, 0);
      o1 = __builtin_amdgcn_mfma_f32_32x32x16_bf16(fb0, vb01, o1, 0, 0, 0);
      o2 = __builtin_amdgcn_mfma_f32_32x32x16_bf16(fb0, vb02, o2, 0, 0, 0);
      o3 = __builtin_amdgcn_mfma_f32_32x32x16_bf16(fb0, vb03, o3, 0, 0, 0);
      o0 = __builtin_amdgcn_mfma_f32_32x32x16_bf16(fb1, vb10, o0, 0, 0, 0);
      o1 = __builtin_amdgcn_mfma_f32_32x32x16_bf16(fb1, vb11, o1, 0, 0, 0);
      o2 = __builtin_amdgcn_mfma_f32_32x32x16_bf16(fb1, vb12, o2, 0, 0, 0);
      o3 = __builtin_amdgcn_mfma_f32_32x32x16_bf16(fb1, vb13, o3, 0, 0, 0);
      __builtin_amdgcn_s_setprio(0);
    }

    __syncthreads();   // drains our stage (vmcnt) + separates K buffers
  }

  // epilogue: O rows at q' = (r&3)+8*(r>>2)+4*hi, col d = dt*32 + c
  float linv = 1.0f / l;
  #pragma unroll
  for (int r = 0; r < 16; ++r) {
    int qp_ = (r & 3) + 8 * (r >> 2) + 4 * hi;
    float li = __shfl(linv, qp_, 64);
    float* op = out + ((size_t)(row0 + qp_) * NH + h) * HD + c;
    op[0]  = o0[r] * li;
    op[32] = o1[r] * li;
    op[64] = o2[r] * li;
    op[96] = o3[r] * li;
  }
}

// ---- fallback (ws too small): direct f32 loads, single tile per iteration ----
__global__ __launch_bounds__(256, 2)
void attn_fwd_slow(const float* __restrict__ q,
                   const float* __restrict__ kp_,
                   const float* __restrict__ vp_,
                   const int* __restrict__ nseq,
                   float* __restrict__ out)
{
  const int bid  = blockIdx.x;
  const int h    = bid & (NH - 1);
  const int rb   = (T_TOK / 128 - 1) - (bid >> 5);
  const int kvh  = h / QREP;
  const int w    = threadIdx.x >> 6;
  const int lane = threadIdx.x & 63;
  const int c    = lane & 31;
  const int hi   = lane >> 5;
  const int B = *nseq, S = T_TOK / B;
  const int row0 = rb * 128 + w * 32;
  const int b = row0 / S, s0 = row0 - b * S, kb = b * S;
  const float sl2e = 0.08838834764831845f * 1.4426950408889634f;
  short8 qf[8];
  {
    const float* qp = q + ((size_t)(row0 + c) * NH + h) * HD + hi * 8;
    #pragma unroll
    for (int dc = 0; dc < 8; ++dc) {
      float4 a  = *reinterpret_cast<const float4*>(qp + dc * 16);
      float4 bq = *reinterpret_cast<const float4*>(qp + dc * 16 + 4);
      int4v wv; wv[0] = (int)pack_bf16(a.x, a.y);   wv[1] = (int)pack_bf16(a.z, a.w);
                wv[2] = (int)pack_bf16(bq.x, bq.y); wv[3] = (int)pack_bf16(bq.z, bq.w);
      qf[dc] = __builtin_bit_cast(short8, wv);
    }
  }
  f32x16 o0 = {}, o1 = {}, o2 = {}, o3 = {};
  float m = -1e30f, l = 0.0f;
  const int ntiles = s0 / 32 + 1;
  for (int t = 0; t < ntiles; ++t) {
    const int key0 = t * 32;
    const size_t koff = ((size_t)(kb + key0 + c) * NKV + kvh) * HD + hi * 8;
    const float* kp = kp_ + koff;
    f32x16 s = {};
    #pragma unroll
    for (int dc = 0; dc < 8; ++dc) {
      float4 a  = *reinterpret_cast<const float4*>(kp + dc * 16);
      float4 bk = *reinterpret_cast<const float4*>(kp + dc * 16 + 4);
      int4v wv; wv[0] = (int)pack_bf16(a.x, a.y);   wv[1] = (int)pack_bf16(a.z, a.w);
                wv[2] = (int)pack_bf16(bk.x, bk.y); wv[3] = (int)pack_bf16(bk.z, bk.w);
      short8 kf = __builtin_bit_cast(short8, wv);
      s = __builtin_amdgcn_mfma_f32_32x32x16_bf16(kf, qf[dc], s, 0, 0, 0);
    }
    if (t == ntiles - 1) {
      const int qs = s0 + c;
      #pragma unroll
      for (int r = 0; r < 16; ++r) {
        int key = key0 + (r & 3) + 8 * (r >> 2) + 4 * hi;
        if (key > qs) s[r] = -1e30f;
      }
    }
    float pm = s[0];
    #pragma unroll
    for (int r = 1; r < 16; ++r) pm = fmaxf(pm, s[r]);
    pm = fmaxf(pm, __shfl_xor(pm, 32));
    if (!__all((pm - m) * sl2e <= 8.0f)) {
      float mn = fmaxf(m, pm);
      float al = __builtin_amdgcn_exp2f(sl2e * (m - mn));
      m = mn; l *= al;
      #pragma unroll
      for (int r = 0; r < 16; ++r) {
        float ar = __shfl(al, (r & 3) + 8 * (r >> 2) + 4 * hi, 64);
        o0[r] *= ar; o1[r] *= ar; o2[r] *= ar; o3[r] *= ar;
      }
    }
    float rs = 0.0f;
    f32x16 p;
    #pragma unroll
    for (int r = 0; r < 16; ++r) {
      p[r] = __builtin_amdgcn_exp2f((s[r] - m) * sl2e);
      rs += p[r];
    }
    rs += __shfl_xor(rs, 32);
    l += rs;
    short8 f0 = p_frag(p, 0, hi), f1 = p_frag(p, 1, hi);
    #pragma unroll
    for (int st = 0; st < 2; ++st) {
      short8 pa = st ? f1 : f0;
      const size_t voff = ((size_t)(kb + key0 + 16*st + 8*hi) * NKV + kvh) * HD + c;
      const float* vp = vp_ + voff;
      float ve[8][4];
      #pragma unroll
      for (int j = 0; j < 8; ++j) {
        const float* vr = vp + (size_t)j * (NKV * HD);
        #pragma unroll
        for (int dt = 0; dt < 4; ++dt) ve[j][dt] = vr[dt * 32];
      }
      #pragma unroll
      for (int dt = 0; dt < 4; ++dt) {
        int4v vb;
        #pragma unroll
        for (int jj = 0; jj < 4; ++jj)
          vb[jj] = (int)pack_bf16(ve[2*jj][dt], ve[2*jj+1][dt]);
        short8 vfx = __builtin_bit_cast(short8, vb);
        if      (dt == 0) o0 = __builtin_amdgcn_mfma_f32_32x32x16_bf16(pa, vfx, o0, 0, 0, 0);
        else if (dt == 1) o1 = __builtin_amdgcn_mfma_f32_32x32x16_bf16(pa, vfx, o1, 0, 0, 0);
        else if (dt == 2) o2 = __builtin_amdgcn_mfma_f32_32x32x16_bf16(pa, vfx, o2, 0, 0, 0);
        else              o3 = __builtin_amdgcn_mfma_f32_32x32x16_bf16(pa, vfx, o3, 0, 0, 0);
      }
    }
  }
  float linv = 1.0f / l;
  #pragma unroll
  for (int r = 0; r < 16; ++r) {
    int qp_ = (r & 3) + 8 * (r >> 2) + 4 * hi;
    float li = __shfl(linv, qp_, 64);
    float* op = out + ((size_t)(row0 + qp_) * NH + h) * HD + c;
    op[0]  = o0[r] * li;
    op[32] = o1[r] * li;
    op[64] = o2[r] * li;
    op[96] = o3[r] * li;
  }
}

extern "C" void kernel_launch(void* const* d_in, const int* in_sizes, int n_in,
                              void* d_out, int out_size, void* d_ws, size_t ws_size,
                              hipStream_t stream) {
  const float* q = (const float*)d_in[0];
  const float* k = (const float*)d_in[1];
  const float* v = (const float*)d_in[2];
  const int* ns  = (const int*)d_in[3];
  float* o       = (float*)d_out;

  const size_t kvElems = (size_t)T_TOK * NKV * HD;  // 4,194,304 per tensor
  dim3 grid((T_TOK / 128) * NH);                    // 1024 blocks

  if (ws_size >= kvElems * 2 * sizeof(unsigned short)) {
    unsigned short* kfbuf = (unsigned short*)d_ws;
    unsigned short* vfbuf = kfbuf + kvElems;
    pack_kv2<<<2 * (T_TOK / 32), 256, 0, stream>>>(k, v, kfbuf, vfbuf, ns);
    attn_fwd_fast<<<grid, dim3(256), 0, stream>>>(q, kfbuf, vfbuf, ns, o);
  } else {
    attn_fwd_slow<<<grid, dim3(256), 0, stream>>>(q, k, v, ns, o);
  }
}